// Round 2
// baseline (382.514 us; speedup 1.0000x reference)
//
#include <hip/hip_runtime.h>
#include <stdint.h>

#define S_LEN 2048
#define HD    128
#define NKV   8
#define NQM   4
#define WIN   1024
#define QB    32
#define KTILE 32
#define KVROW (NKV * HD)        /* 1024 elements per K/V token row */
#define QROW  (NQM * NKV * HD)  /* 4096 elements per Q/out token row */

typedef __attribute__((ext_vector_type(8))) short bf16x8;
typedef __attribute__((ext_vector_type(4))) float f32x4;
typedef __attribute__((ext_vector_type(4))) int   i32x4;

__device__ __forceinline__ uint32_t f2bf(float f) {
  uint32_t x = __builtin_bit_cast(uint32_t, f);
  x += 0x7fffu + ((x >> 16) & 1u);   // RNE
  return x >> 16;
}

// load 8 consecutive "bf16-worth" elements starting at p (packed 2/dword)
__device__ __forceinline__ void load8bf(const uint16_t* p, uint32_t o[4]) {
  i32x4 v = *reinterpret_cast<const i32x4*>(p);
  o[0] = (uint32_t)v[0]; o[1] = (uint32_t)v[1]; o[2] = (uint32_t)v[2]; o[3] = (uint32_t)v[3];
}
__device__ __forceinline__ void load8bf(const float* p, uint32_t o[4]) {
  float4 a = *reinterpret_cast<const float4*>(p);
  float4 b = *reinterpret_cast<const float4*>(p + 4);
  o[0] = f2bf(a.x) | (f2bf(a.y) << 16);
  o[1] = f2bf(a.z) | (f2bf(a.w) << 16);
  o[2] = f2bf(b.x) | (f2bf(b.y) << 16);
  o[3] = f2bf(b.z) | (f2bf(b.w) << 16);
}

__global__ void cvt_kernel(const float* __restrict__ in, uint16_t* __restrict__ out, int n4) {
  int i = blockIdx.x * blockDim.x + threadIdx.x;
  int stride = gridDim.x * blockDim.x;
  for (int j = i; j < n4; j += stride) {
    float4 v = reinterpret_cast<const float4*>(in)[j];
    ushort4 o;
    o.x = (uint16_t)f2bf(v.x); o.y = (uint16_t)f2bf(v.y);
    o.z = (uint16_t)f2bf(v.z); o.w = (uint16_t)f2bf(v.w);
    reinterpret_cast<ushort4*>(out)[j] = o;
  }
}

// V^T LDS column swizzle: conflict-free per quarter-wave for both the
// transpose-scatter writes (spread by d>>3) and the PV b-frag reads (spread by d&7)
#define VSWZ(d) (((((uint32_t)(d) >> 3) ^ (uint32_t)(d)) & 7u) << 3)

template <typename KVT>
__launch_bounds__(256, 3)
__global__ void attn_kernel(const float* __restrict__ Q,
                            const KVT* __restrict__ Ksrc,
                            const KVT* __restrict__ Vsrc,
                            const float* __restrict__ sinks,
                            float* __restrict__ out) {
  // LDS: K tiles  2 x (32 x 256B, 16B-swizzled)   : 16 KB
  //      V^T tiles 2 x (128 x 64B, 8B-swizzled)   : 16 KB
  //      P scratch, 2 KB per wave (8B-swizzled)   : 8 KB
  __shared__ __align__(16) uint8_t smem[40960];

  const int tid  = threadIdx.x;
  const int lane = tid & 63;
  const int wv   = tid >> 6;
  const int c    = lane & 15;   // "16-dim" lane coordinate
  const int g    = lane >> 4;   // lane group 0..3
  uint8_t* pls = smem + 32768 + wv * 2048;

  // work-complement remap: blocks 256 apart in linear id get q-tiles
  // {0,16,32,48} apart (complementary work); heavy tiles dispatch first (LPT)
  const int qt = 63 - ((blockIdx.x + 4 * (blockIdx.y + 8 * blockIdx.z)) & 63);
  const int q0   = qt * QB;
  const int kv   = blockIdx.y;
  const int b    = blockIdx.z;
  const int head = kv * NQM + wv;

  // ---------------- Q fragments (bf16, SM_SCALE*log2e folded in) ----------------
  const float SCALE2 = 0.08838834764831845f * 1.4426950408889634f;  // 1/sqrt(128) * log2(e)
  bf16x8 qf[2][4];
  #pragma unroll
  for (int tq = 0; tq < 2; ++tq) {
    const float* qp = Q + (size_t)(b * S_LEN + q0 + tq * 16 + c) * QROW + head * HD;
    #pragma unroll
    for (int f = 0; f < 4; ++f) {
      int d0 = f * 32 + g * 8;
      float4 a = *reinterpret_cast<const float4*>(qp + d0);
      float4 bb = *reinterpret_cast<const float4*>(qp + d0 + 4);
      i32x4 t;
      t[0] = (int)(f2bf(a.x * SCALE2) | (f2bf(a.y * SCALE2) << 16));
      t[1] = (int)(f2bf(a.z * SCALE2) | (f2bf(a.w * SCALE2) << 16));
      t[2] = (int)(f2bf(bb.x * SCALE2) | (f2bf(bb.y * SCALE2) << 16));
      t[3] = (int)(f2bf(bb.z * SCALE2) | (f2bf(bb.w * SCALE2) << 16));
      qf[tq][f] = __builtin_bit_cast(bf16x8, t);
    }
  }

  // online-softmax state in log2 domain; sink is an initial column: m = sink*log2e, l = 1
  const float sinkv = sinks[head] * 1.4426950408889634f;
  float m_[2] = {sinkv, sinkv};
  float l_[2] = {1.0f, 1.0f};
  f32x4 acc[2][8];
  #pragma unroll
  for (int tq = 0; tq < 2; ++tq)
    #pragma unroll
    for (int dt = 0; dt < 8; ++dt) acc[tq][dt] = (f32x4)0.0f;

  // ---------------- staging coordinates ----------------
  const int kr  = tid >> 3;            // K row 0..31
  const int kcB = (tid & 7) * 32;      // K column byte
  const uint32_t kw0 = (uint32_t)(kr * 256 + ((kcB)      ^ ((kr & 7) << 4)));
  const uint32_t kw1 = (uint32_t)(kr * 256 + ((kcB + 16) ^ ((kr & 7) << 4)));
  const KVT* kg = Ksrc + (size_t)(b * S_LEN) * KVROW + kv * HD + (tid & 7) * 16;
  const int va = tid >> 4;             // V key-pair 0..15
  const int vd = tid & 15;             // V d-chunk
  const KVT* vg = Vsrc + (size_t)(b * S_LEN) * KVROW + kv * HD + vd * 8;

  int kstart = q0 - (WIN - 1);
  if (kstart < 0) kstart = 0;
  kstart &= ~(KTILE - 1);

  uint32_t kst[8], vr0[4], vr1[4];

  // ---- prologue: load + write tile kstart into buffer 0 ----
  {
    const KVT* ks = kg + (size_t)(kstart + kr) * KVROW;
    load8bf(ks, kst); load8bf(ks + 8, kst + 4);
    const KVT* vs = vg + (size_t)(kstart + 2 * va) * KVROW;
    load8bf(vs, vr0); load8bf(vs + KVROW, vr1);
  }
  uint8_t* kcur = smem;         uint8_t* kalt = smem + 8192;
  uint8_t* vcur = smem + 16384; uint8_t* valt = smem + 24576;
  {
    i32x4 w0, w1;
    w0[0]=(int)kst[0]; w0[1]=(int)kst[1]; w0[2]=(int)kst[2]; w0[3]=(int)kst[3];
    w1[0]=(int)kst[4]; w1[1]=(int)kst[5]; w1[2]=(int)kst[6]; w1[3]=(int)kst[7];
    *reinterpret_cast<i32x4*>(kcur + kw0) = w0;
    *reinterpret_cast<i32x4*>(kcur + kw1) = w1;
    #pragma unroll
    for (int i = 0; i < 8; ++i) {
      int d = vd * 8 + i;
      uint32_t lo = (i & 1) ? (vr0[i >> 1] >> 16) : (vr0[i >> 1] & 0xffffu);
      uint32_t hi = (i & 1) ? (vr1[i >> 1] >> 16) : (vr1[i >> 1] & 0xffffu);
      uint32_t byte = (uint32_t)(d * 64) + (((uint32_t)(va * 4)) ^ VSWZ(d));
      *reinterpret_cast<uint32_t*>(vcur + byte) = lo | (hi << 16);
    }
  }
  __syncthreads();

  const uint32_t sp = ((uint32_t)(c & 7)) << 3;   // P swizzle (row&7 == c&7)

  for (int kt = kstart; kt <= q0; kt += KTILE) {
    const bool more = (kt + KTILE) <= q0;
    // ---- issue next tile's global loads EARLY (latency hides under compute) ----
    if (more) {
      const KVT* ks = kg + (size_t)(kt + KTILE + kr) * KVROW;
      load8bf(ks, kst); load8bf(ks + 8, kst + 4);
      const KVT* vs = vg + (size_t)(kt + KTILE + 2 * va) * KVROW;
      load8bf(vs, vr0); load8bf(vs + KVROW, vr1);
    }

    // ---- QK^T (swapped: St[key][q]) ----
    f32x4 st[2][2];
    #pragma unroll
    for (int a_ = 0; a_ < 2; ++a_)
      #pragma unroll
      for (int b_ = 0; b_ < 2; ++b_) st[a_][b_] = (f32x4)0.0f;

    __builtin_amdgcn_s_setprio(1);
    #pragma unroll
    for (int kt_ = 0; kt_ < 2; ++kt_) {
      bf16x8 kf[4];
      #pragma unroll
      for (int f = 0; f < 4; ++f) {
        int row = kt_ * 16 + c;
        uint32_t byte = (uint32_t)(row * 256 + ((f * 64 + g * 16) ^ ((row & 7) << 4)));
        kf[f] = *reinterpret_cast<const bf16x8*>(kcur + byte);
      }
      #pragma unroll
      for (int tq = 0; tq < 2; ++tq)
        #pragma unroll
        for (int f = 0; f < 4; ++f)
          st[kt_][tq] = __builtin_amdgcn_mfma_f32_16x16x32_bf16(kf[f], qf[tq][f], st[kt_][tq], 0, 0, 0);
    }
    __builtin_amdgcn_s_setprio(0);

    // ---- mask (edge tiles only; wave-uniform branch) ----
    const bool need_mask = (kt + KTILE - 1 > q0) || (kt < q0 + QB - WIN);
    if (need_mask) {
      #pragma unroll
      for (int kt_ = 0; kt_ < 2; ++kt_)
        #pragma unroll
        for (int tq = 0; tq < 2; ++tq)
          #pragma unroll
          for (int r = 0; r < 4; ++r) {
            int k_ = kt + kt_ * 16 + g * 4 + r;
            int q_ = q0 + tq * 16 + c;
            bool ok = (k_ <= q_) && (k_ > q_ - WIN);
            if (!ok) st[kt_][tq][r] = -1e38f;
          }
    }

    // ---- online softmax (log2 domain, defer-rescale) + P->LDS ----
    #pragma unroll
    for (int tq = 0; tq < 2; ++tq) {
      float vmax = fmaxf(fmaxf(fmaxf(st[0][tq][0], st[0][tq][1]), fmaxf(st[0][tq][2], st[0][tq][3])),
                         fmaxf(fmaxf(st[1][tq][0], st[1][tq][1]), fmaxf(st[1][tq][2], st[1][tq][3])));
      vmax = fmaxf(vmax, __shfl_xor(vmax, 16));
      vmax = fmaxf(vmax, __shfl_xor(vmax, 32));
      const float mold = m_[tq];
      // defer-rescale (T13): keep old max while P stays bounded by 2^11.54 = e^8
      if (!__all(vmax <= mold + 11.54f)) {
        float mnew = fmaxf(mold, vmax);
        float scl  = exp2f(mold - mnew);
        m_[tq] = mnew;
        l_[tq] *= scl;
        float sc[4];
        #pragma unroll
        for (int r = 0; r < 4; ++r) sc[r] = __shfl(scl, (lane & 48) | (g * 4 + r));
        #pragma unroll
        for (int dt = 0; dt < 8; ++dt)
          #pragma unroll
          for (int r = 0; r < 4; ++r) acc[tq][dt][r] *= sc[r];
      }
      const float mrun = m_[tq];
      float p[2][4];
      float s = 0.0f;
      #pragma unroll
      for (int kt_ = 0; kt_ < 2; ++kt_)
        #pragma unroll
        for (int r = 0; r < 4; ++r) {
          float e = exp2f(st[kt_][tq][r] - mrun);
          p[kt_][r] = e;
          s += e;
        }
      s += __shfl_xor(s, 16);
      s += __shfl_xor(s, 32);
      l_[tq] += s;
      // pack P (bf16) into per-wave LDS: P[q][k], rows 64B, 8B-swizzled
      #pragma unroll
      for (int kt_ = 0; kt_ < 2; ++kt_) {
        uint32_t lo = f2bf(p[kt_][0]) | (f2bf(p[kt_][1]) << 16);
        uint32_t hi = f2bf(p[kt_][2]) | (f2bf(p[kt_][3]) << 16);
        uint32_t byte = (uint32_t)((tq * 16 + c) * 64) + (((uint32_t)(kt_ * 32 + g * 8)) ^ sp);
        uint2 pk; pk.x = lo; pk.y = hi;
        *reinterpret_cast<uint2*>(pls + byte) = pk;
      }
    }

    // ---- PV ----
    bf16x8 pa[2];
    #pragma unroll
    for (int tq = 0; tq < 2; ++tq) {
      uint32_t base = (uint32_t)((tq * 16 + c) * 64);
      uint2 plo = *reinterpret_cast<const uint2*>(pls + base + (((uint32_t)(g * 16))     ^ sp));
      uint2 phi = *reinterpret_cast<const uint2*>(pls + base + (((uint32_t)(g * 16 + 8)) ^ sp));
      i32x4 pv; pv[0] = (int)plo.x; pv[1] = (int)plo.y; pv[2] = (int)phi.x; pv[3] = (int)phi.y;
      pa[tq] = __builtin_bit_cast(bf16x8, pv);
    }
    __builtin_amdgcn_s_setprio(1);
    #pragma unroll
    for (int dt = 0; dt < 8; ++dt) {
      int d = dt * 16 + c;
      uint32_t rowb = (uint32_t)(d * 64);
      uint32_t swz  = VSWZ(d);
      uint2 lo = *reinterpret_cast<const uint2*>(vcur + rowb + (((uint32_t)(g * 16))     ^ swz));
      uint2 hi = *reinterpret_cast<const uint2*>(vcur + rowb + (((uint32_t)(g * 16 + 8)) ^ swz));
      i32x4 vv; vv[0] = (int)lo.x; vv[1] = (int)lo.y; vv[2] = (int)hi.x; vv[3] = (int)hi.y;
      bf16x8 vf = __builtin_bit_cast(bf16x8, vv);
      #pragma unroll
      for (int tq = 0; tq < 2; ++tq)
        acc[tq][dt] = __builtin_amdgcn_mfma_f32_16x16x32_bf16(pa[tq], vf, acc[tq][dt], 0, 0, 0);
    }
    __builtin_amdgcn_s_setprio(0);

    // ---- write next tile into the alternate buffers (reads of them finished last iter) ----
    if (more) {
      i32x4 w0, w1;
      w0[0]=(int)kst[0]; w0[1]=(int)kst[1]; w0[2]=(int)kst[2]; w0[3]=(int)kst[3];
      w1[0]=(int)kst[4]; w1[1]=(int)kst[5]; w1[2]=(int)kst[6]; w1[3]=(int)kst[7];
      *reinterpret_cast<i32x4*>(kalt + kw0) = w0;
      *reinterpret_cast<i32x4*>(kalt + kw1) = w1;
      #pragma unroll
      for (int i = 0; i < 8; ++i) {
        int d = vd * 8 + i;
        uint32_t lo = (i & 1) ? (vr0[i >> 1] >> 16) : (vr0[i >> 1] & 0xffffu);
        uint32_t hi = (i & 1) ? (vr1[i >> 1] >> 16) : (vr1[i >> 1] & 0xffffu);
        uint32_t byte = (uint32_t)(d * 64) + (((uint32_t)(va * 4)) ^ VSWZ(d));
        *reinterpret_cast<uint32_t*>(valt + byte) = lo | (hi << 16);
      }
    }
    __syncthreads();
    uint8_t* t0 = kcur; kcur = kalt; kalt = t0;
    uint8_t* t1 = vcur; vcur = valt; valt = t1;
  }

  // ---------------- epilogue: O /= l, store ----------------
  #pragma unroll
  for (int tq = 0; tq < 2; ++tq) {
    float linv = 1.0f / l_[tq];
    float li[4];
    #pragma unroll
    for (int r = 0; r < 4; ++r) li[r] = __shfl(linv, (lane & 48) | (g * 4 + r));
    #pragma unroll
    for (int dt = 0; dt < 8; ++dt)
      #pragma unroll
      for (int r = 0; r < 4; ++r) {
        size_t o = (size_t)(b * S_LEN + q0 + tq * 16 + g * 4 + r) * QROW + head * HD + dt * 16 + c;
        out[o] = acc[tq][dt][r] * li[r];
      }
  }
}

extern "C" void kernel_launch(void* const* d_in, const int* in_sizes, int n_in,
                              void* d_out, int out_size, void* d_ws, size_t ws_size,
                              hipStream_t stream) {
  const float* Q     = (const float*)d_in[0];
  const float* K     = (const float*)d_in[1];
  const float* V     = (const float*)d_in[2];
  const float* sinks = (const float*)d_in[3];
  float* out = (float*)d_out;

  const int nK = in_sizes[1];                       // B*S*NKV*HD
  const int B  = in_sizes[0] / (S_LEN * QROW);
  dim3 grid(S_LEN / QB, NKV, B);

  const size_t need = (size_t)nK * 2u * 2u;         // Kbf + Vbf in bf16
  if (ws_size >= need) {
    uint16_t* Kb = (uint16_t*)d_ws;
    uint16_t* Vb = Kb + nK;
    cvt_kernel<<<1024, 256, 0, stream>>>(K, Kb, nK / 4);
    cvt_kernel<<<1024, 256, 0, stream>>>(V, Vb, nK / 4);
    attn_kernel<uint16_t><<<grid, 256, 0, stream>>>(Q, Kb, Vb, sinks, out);
  } else {
    attn_kernel<float><<<grid, 256, 0, stream>>>(Q, K, V, sinks, out);
  }
}

// Round 5
// 247.326 us; speedup vs baseline: 1.5466x; 1.5466x over previous
//
#include <hip/hip_runtime.h>
#include <stdint.h>

#define S_LEN 2048
#define HD    128
#define NKV   8
#define NQM   4
#define WIN   1024
#define QB    32
#define KTILE 32
#define KVROW (NKV * HD)        /* 1024 elements per K/V token row */
#define QROW  (NQM * NKV * HD)  /* 4096 elements per Q/out token row */

typedef __attribute__((ext_vector_type(8))) short bf16x8;
typedef __attribute__((ext_vector_type(4))) float f32x4;
typedef __attribute__((ext_vector_type(4))) int   i32x4;

__device__ __forceinline__ uint32_t f2bf(float f) {
  uint32_t x = __builtin_bit_cast(uint32_t, f);
  x += 0x7fffu + ((x >> 16) & 1u);   // RNE
  return x >> 16;
}

// load 8 consecutive "bf16-worth" elements starting at p (packed 2/dword)
__device__ __forceinline__ void load8bf(const uint16_t* p, uint32_t o[4]) {
  i32x4 v = *reinterpret_cast<const i32x4*>(p);
  o[0] = (uint32_t)v[0]; o[1] = (uint32_t)v[1]; o[2] = (uint32_t)v[2]; o[3] = (uint32_t)v[3];
}
__device__ __forceinline__ void load8bf(const float* p, uint32_t o[4]) {
  float4 a = *reinterpret_cast<const float4*>(p);
  float4 b = *reinterpret_cast<const float4*>(p + 4);
  o[0] = f2bf(a.x) | (f2bf(a.y) << 16);
  o[1] = f2bf(a.z) | (f2bf(a.w) << 16);
  o[2] = f2bf(b.x) | (f2bf(b.y) << 16);
  o[3] = f2bf(b.z) | (f2bf(b.w) << 16);
}

__global__ void cvt_kernel(const float* __restrict__ in, uint16_t* __restrict__ out, int n4) {
  int i = blockIdx.x * blockDim.x + threadIdx.x;
  int stride = gridDim.x * blockDim.x;
  for (int j = i; j < n4; j += stride) {
    float4 v = reinterpret_cast<const float4*>(in)[j];
    ushort4 o;
    o.x = (uint16_t)f2bf(v.x); o.y = (uint16_t)f2bf(v.y);
    o.z = (uint16_t)f2bf(v.z); o.w = (uint16_t)f2bf(v.w);
    reinterpret_cast<ushort4*>(out)[j] = o;
  }
}

// V^T LDS column swizzle: conflict-free (<=2-way) for both the transpose-scatter
// writes (spread by d>>3) and the PV b-frag reads (spread by d&7)
#define VSWZ(d) (((((uint32_t)(d) >> 3) ^ (uint32_t)(d)) & 7u) << 3)

template <typename KVT>
__launch_bounds__(256, 2)
__global__ void attn_kernel(const float* __restrict__ Q,
                            const KVT* __restrict__ Ksrc,
                            const KVT* __restrict__ Vsrc,
                            const float* __restrict__ sinks,
                            float* __restrict__ out) {
  // LDS: K tiles  2 x (32 x 256B, 16B-swizzled)   : 16 KB   @ 0
  //      V^T tiles 2 x (128 x 64B, 8B-swizzled)   : 16 KB   @ 16384
  //      P scratch, 2 KB per wave (8B-swizzled)   : 8 KB    @ 32768
  __shared__ __align__(16) uint8_t smem[40960];

  const int tid  = threadIdx.x;
  const int lane = tid & 63;
  const int wv   = tid >> 6;
  const int c    = lane & 15;   // "16-dim" lane coordinate
  const int g    = lane >> 4;   // lane group 0..3
  uint8_t* pls = smem + 32768 + wv * 2048;

  // ---- block decode: kv = bid&7 keeps each kv's K/V on one XCD's L2 ----
  const int bid = blockIdx.x;
  const int kv  = bid & 7;
  const int i2  = bid >> 3;          // 0 .. 48*B-1
  const int b   = i2 / 48;
  const int pairIdx = i2 % 48;
  const int head = kv * NQM + wv;
  const float sink_l2 = sinks[head] * 1.4426950408889634f;

  // tile pairing: work(qt) = qt+1 tiles for qt<32, 33 for qt>=32.
  // pair (31-p, p) -> 33; singles 32..63 -> 33. Every block = 33 k-iters.
  int qtA, qtB, nrep;
  if (pairIdx < 16) { qtA = 31 - pairIdx; qtB = pairIdx; nrep = 2; }
  else              { qtA = pairIdx + 16; qtB = 0;       nrep = 1; }

  // ---------------- staging coordinates ----------------
  const int kr  = tid >> 3;            // K row 0..31 (fp32 path)
  const int kcB = (tid & 7) * 32;      // K column byte (fp32 path)
  const uint32_t kw0 = (uint32_t)(kr * 256 + ((kcB)      ^ ((kr & 7) << 4)));
  const uint32_t kw1 = (uint32_t)(kr * 256 + ((kcB + 16) ^ ((kr & 7) << 4)));
  const KVT* kg = Ksrc + (size_t)(b * S_LEN) * KVROW + kv * HD + (tid & 7) * 16;
  const size_t kbase = (size_t)(b * S_LEN) * KVROW + kv * HD;   // elems
  const int va = tid >> 4;             // V key-pair 0..15
  const int vd = tid & 15;             // V d-chunk
  const KVT* vg = Vsrc + (size_t)(b * S_LEN) * KVROW + kv * HD + vd * 8;

  uint32_t vr0[4], vr1[4];

  // async K stage: linear LDS dest (wave-uniform base + lane*16), swizzle
  // applied on the per-lane GLOBAL source address (m173 pattern)
  auto stageK = [&](uint8_t* kbuf, int kt) {
    if constexpr (sizeof(KVT) == 2) {
      #pragma unroll
      for (int ch = 0; ch < 2; ++ch) {
        const int o    = wv * 2048 + ch * 1024 + lane * 16;
        const int row  = o >> 8;
        const int scol = (o & 255) ^ ((row & 7) << 4);
        const uint8_t* gp = (const uint8_t*)(Ksrc + kbase + (size_t)(kt + row) * KVROW) + scol;
        __builtin_amdgcn_global_load_lds(
            (const __attribute__((address_space(1))) void*)gp,
            (__attribute__((address_space(3))) void*)(kbuf + wv * 2048 + ch * 1024),
            16, 0, 0);
      }
    } else {
      const KVT* src = kg + (size_t)(kt + kr) * KVROW;
      uint32_t t0[4], t1[4];
      load8bf(src, t0); load8bf(src + 8, t1);
      i32x4 w0, w1;
      w0[0]=(int)t0[0]; w0[1]=(int)t0[1]; w0[2]=(int)t0[2]; w0[3]=(int)t0[3];
      w1[0]=(int)t1[0]; w1[1]=(int)t1[1]; w1[2]=(int)t1[2]; w1[3]=(int)t1[3];
      *reinterpret_cast<i32x4*>(kbuf + kw0) = w0;
      *reinterpret_cast<i32x4*>(kbuf + kw1) = w1;
    }
  };
  auto loadV = [&](int kt) {
    const KVT* vs = vg + (size_t)(kt + 2 * va) * KVROW;
    load8bf(vs, vr0); load8bf(vs + KVROW, vr1);
  };
  auto writeV = [&](uint8_t* vbuf) {
    #pragma unroll
    for (int ii = 0; ii < 8; ++ii) {
      int d = vd * 8 + ii;
      uint32_t lo = (ii & 1) ? (vr0[ii >> 1] >> 16) : (vr0[ii >> 1] & 0xffffu);
      uint32_t hi = (ii & 1) ? (vr1[ii >> 1] >> 16) : (vr1[ii >> 1] & 0xffffu);
      uint32_t byte = (uint32_t)(d * 64) + (((uint32_t)(va * 4)) ^ VSWZ(d));
      *reinterpret_cast<uint32_t*>(vbuf + byte) = lo | (hi << 16);
    }
  };

  const float SCALE2 = 0.08838834764831845f * 1.4426950408889634f;  // 1/sqrt(128)*log2e
  const uint32_t sp = ((uint32_t)(c & 7)) << 3;   // P swizzle (row&7 == c&7)

  for (int rep = 0; rep < nrep; ++rep) {
    const int q0 = (rep ? qtB : qtA) * QB;

    // -------- Q fragments (bf16, SM_SCALE*log2e folded in) --------
    bf16x8 qf[2][4];
    #pragma unroll
    for (int tq = 0; tq < 2; ++tq) {
      const float* qp = Q + (size_t)(b * S_LEN + q0 + tq * 16 + c) * QROW + head * HD;
      #pragma unroll
      for (int f = 0; f < 4; ++f) {
        int d0 = f * 32 + g * 8;
        float4 a = *reinterpret_cast<const float4*>(qp + d0);
        float4 bb = *reinterpret_cast<const float4*>(qp + d0 + 4);
        i32x4 t;
        t[0] = (int)(f2bf(a.x * SCALE2) | (f2bf(a.y * SCALE2) << 16));
        t[1] = (int)(f2bf(a.z * SCALE2) | (f2bf(a.w * SCALE2) << 16));
        t[2] = (int)(f2bf(bb.x * SCALE2) | (f2bf(bb.y * SCALE2) << 16));
        t[3] = (int)(f2bf(bb.z * SCALE2) | (f2bf(bb.w * SCALE2) << 16));
        qf[tq][f] = __builtin_bit_cast(bf16x8, t);
      }
    }

    // online-softmax state (log2 domain); sink = initial column: m=sink*log2e, l=1
    float m_[2] = {sink_l2, sink_l2};
    float l_[2] = {1.0f, 1.0f};
    f32x4 acc[2][8];
    #pragma unroll
    for (int tq = 0; tq < 2; ++tq)
      #pragma unroll
      for (int dt = 0; dt < 8; ++dt) acc[tq][dt] = (f32x4)0.0f;

    int kstart = q0 - (WIN - 1);
    if (kstart < 0) kstart = 0;
    kstart &= ~(KTILE - 1);

    uint8_t* kcur = smem;         uint8_t* kalt = smem + 8192;
    uint8_t* vcur = smem + 16384; uint8_t* valt = smem + 24576;

    // prologue: stage first tile
    loadV(kstart);
    stageK(kcur, kstart);
    writeV(vcur);
    __syncthreads();

    for (int kt = kstart; kt <= q0; kt += KTILE) {
      const bool more = (kt + KTILE) <= q0;
      if (more) {           // issue next tile's loads EARLY (K async, V to regs)
        stageK(kalt, kt + KTILE);
        loadV(kt + KTILE);
      }

      // ---- QK^T (swapped: St[key][q]) ----
      f32x4 st[2][2];
      #pragma unroll
      for (int a_ = 0; a_ < 2; ++a_)
        #pragma unroll
        for (int b_ = 0; b_ < 2; ++b_) st[a_][b_] = (f32x4)0.0f;

      __builtin_amdgcn_s_setprio(1);
      #pragma unroll
      for (int kt_ = 0; kt_ < 2; ++kt_) {
        bf16x8 kf[4];
        #pragma unroll
        for (int f = 0; f < 4; ++f) {
          int row = kt_ * 16 + c;
          uint32_t byte = (uint32_t)(row * 256 + ((f * 64 + g * 16) ^ ((row & 7) << 4)));
          kf[f] = *reinterpret_cast<const bf16x8*>(kcur + byte);
        }
        #pragma unroll
        for (int tq = 0; tq < 2; ++tq)
          #pragma unroll
          for (int f = 0; f < 4; ++f)
            st[kt_][tq] = __builtin_amdgcn_mfma_f32_16x16x32_bf16(kf[f], qf[tq][f], st[kt_][tq], 0, 0, 0);
      }
      __builtin_amdgcn_s_setprio(0);

      // ---- mask (edge tiles only; wave-uniform branch) ----
      const bool need_mask = (kt + KTILE - 1 > q0) || (kt < q0 + QB - WIN);
      if (need_mask) {
        #pragma unroll
        for (int kt_ = 0; kt_ < 2; ++kt_)
          #pragma unroll
          for (int tq = 0; tq < 2; ++tq)
            #pragma unroll
            for (int r = 0; r < 4; ++r) {
              int k_ = kt + kt_ * 16 + g * 4 + r;
              int q_ = q0 + tq * 16 + c;
              bool ok = (k_ <= q_) && (k_ > q_ - WIN);
              if (!ok) st[kt_][tq][r] = -1e38f;
            }
      }

      // ---- online softmax (log2 domain, defer-rescale) + P->LDS ----
      #pragma unroll
      for (int tq = 0; tq < 2; ++tq) {
        float vmax = fmaxf(fmaxf(fmaxf(st[0][tq][0], st[0][tq][1]), fmaxf(st[0][tq][2], st[0][tq][3])),
                           fmaxf(fmaxf(st[1][tq][0], st[1][tq][1]), fmaxf(st[1][tq][2], st[1][tq][3])));
        vmax = fmaxf(vmax, __shfl_xor(vmax, 16));
        vmax = fmaxf(vmax, __shfl_xor(vmax, 32));
        const float mold = m_[tq];
        if (!__all(vmax <= mold + 11.54f)) {    // T13: P bounded by 2^11.54 = e^8
          float mnew = fmaxf(mold, vmax);
          float scl  = exp2f(mold - mnew);
          m_[tq] = mnew;
          l_[tq] *= scl;
          float sc[4];
          #pragma unroll
          for (int r = 0; r < 4; ++r) sc[r] = __shfl(scl, (lane & 48) | (g * 4 + r));
          #pragma unroll
          for (int dt = 0; dt < 8; ++dt)
            #pragma unroll
            for (int r = 0; r < 4; ++r) acc[tq][dt][r] *= sc[r];
        }
        const float mrun = m_[tq];
        float p[2][4];
        float s = 0.0f;
        #pragma unroll
        for (int kt_ = 0; kt_ < 2; ++kt_)
          #pragma unroll
          for (int r = 0; r < 4; ++r) {
            float e = exp2f(st[kt_][tq][r] - mrun);
            p[kt_][r] = e;
            s += e;
          }
        s += __shfl_xor(s, 16);
        s += __shfl_xor(s, 32);
        l_[tq] += s;
        #pragma unroll
        for (int kt_ = 0; kt_ < 2; ++kt_) {
          uint32_t lo = f2bf(p[kt_][0]) | (f2bf(p[kt_][1]) << 16);
          uint32_t hi = f2bf(p[kt_][2]) | (f2bf(p[kt_][3]) << 16);
          uint32_t byte = (uint32_t)((tq * 16 + c) * 64) + (((uint32_t)(kt_ * 32 + g * 8)) ^ sp);
          uint2 pk; pk.x = lo; pk.y = hi;
          *reinterpret_cast<uint2*>(pls + byte) = pk;
        }
      }

      // ---- PV ----
      bf16x8 pa[2];
      #pragma unroll
      for (int tq = 0; tq < 2; ++tq) {
        uint32_t base = (uint32_t)((tq * 16 + c) * 64);
        uint2 plo = *reinterpret_cast<const uint2*>(pls + base + (((uint32_t)(g * 16))     ^ sp));
        uint2 phi = *reinterpret_cast<const uint2*>(pls + base + (((uint32_t)(g * 16 + 8)) ^ sp));
        i32x4 pv; pv[0] = (int)plo.x; pv[1] = (int)plo.y; pv[2] = (int)phi.x; pv[3] = (int)phi.y;
        pa[tq] = __builtin_bit_cast(bf16x8, pv);
      }
      __builtin_amdgcn_s_setprio(1);
      #pragma unroll
      for (int dt = 0; dt < 8; ++dt) {
        int d = dt * 16 + c;
        uint32_t rowb = (uint32_t)(d * 64);
        uint32_t swz  = VSWZ(d);
        uint2 lo = *reinterpret_cast<const uint2*>(vcur + rowb + (((uint32_t)(g * 16))     ^ swz));
        uint2 hi = *reinterpret_cast<const uint2*>(vcur + rowb + (((uint32_t)(g * 16 + 8)) ^ swz));
        i32x4 vv; vv[0] = (int)lo.x; vv[1] = (int)lo.y; vv[2] = (int)hi.x; vv[3] = (int)hi.y;
        bf16x8 vf = __builtin_bit_cast(bf16x8, vv);
        #pragma unroll
        for (int tq = 0; tq < 2; ++tq)
          acc[tq][dt] = __builtin_amdgcn_mfma_f32_16x16x32_bf16(pa[tq], vf, acc[tq][dt], 0, 0, 0);
      }
      __builtin_amdgcn_s_setprio(0);

      // ---- write next V tile into alternate buffer (T14 write-late) ----
      if (more) writeV(valt);
      __syncthreads();
      uint8_t* t0 = kcur; kcur = kalt; kalt = t0;
      uint8_t* t1 = vcur; vcur = valt; valt = t1;
    }

    // -------- epilogue: O /= l, store --------
    #pragma unroll
    for (int tq = 0; tq < 2; ++tq) {
      float linv = 1.0f / l_[tq];
      float li[4];
      #pragma unroll
      for (int r = 0; r < 4; ++r) li[r] = __shfl(linv, (lane & 48) | (g * 4 + r));
      #pragma unroll
      for (int dt = 0; dt < 8; ++dt)
        #pragma unroll
        for (int r = 0; r < 4; ++r) {
          size_t o = (size_t)(b * S_LEN + q0 + tq * 16 + g * 4 + r) * QROW + head * HD + dt * 16 + c;
          out[o] = acc[tq][dt][r] * li[r];
        }
    }
  }
}

extern "C" void kernel_launch(void* const* d_in, const int* in_sizes, int n_in,
                              void* d_out, int out_size, void* d_ws, size_t ws_size,
                              hipStream_t stream) {
  const float* Q     = (const float*)d_in[0];
  const float* K     = (const float*)d_in[1];
  const float* V     = (const float*)d_in[2];
  const float* sinks = (const float*)d_in[3];
  float* out = (float*)d_out;

  const int nK = in_sizes[1];                       // B*S*NKV*HD
  const int B  = in_sizes[0] / (S_LEN * QROW);
  dim3 grid(384 * B);                               // 48 uniform blocks per (kv,b)

  const size_t need = (size_t)nK * 2u * 2u;         // Kbf + Vbf in bf16
  if (ws_size >= need) {
    uint16_t* Kb = (uint16_t*)d_ws;
    uint16_t* Vb = Kb + nK;
    cvt_kernel<<<1024, 256, 0, stream>>>(K, Kb, nK / 4);
    cvt_kernel<<<1024, 256, 0, stream>>>(V, Vb, nK / 4);
    attn_kernel<uint16_t><<<grid, 256, 0, stream>>>(Q, Kb, Vb, sinks, out);
  } else {
    attn_kernel<float><<<grid, 256, 0, stream>>>(Q, K, V, sinks, out);
  }
}

// Round 6
// 226.428 us; speedup vs baseline: 1.6893x; 1.0923x over previous
//
#include <hip/hip_runtime.h>
#include <stdint.h>

#define S_LEN 2048
#define HD    128
#define NKV   8
#define NQM   4
#define WIN   1024
#define QB    32
#define KTILE 32
#define KVROW (NKV * HD)        /* 1024 elements per K/V token row */
#define QROW  (NQM * NKV * HD)  /* 4096 elements per Q/out token row */

typedef __attribute__((ext_vector_type(8))) short bf16x8;
typedef __attribute__((ext_vector_type(4))) float f32x4;
typedef __attribute__((ext_vector_type(4))) int   i32x4;

__device__ __forceinline__ uint32_t f2bf(float f) {
  uint32_t x = __builtin_bit_cast(uint32_t, f);
  x += 0x7fffu + ((x >> 16) & 1u);   // RNE
  return x >> 16;
}

// pack two f32 -> one dword of 2 bf16 (lo, hi), single HW op
__device__ __forceinline__ uint32_t cvtpk(float lo, float hi) {
  uint32_t r;
  asm("v_cvt_pk_bf16_f32 %0, %1, %2" : "=v"(r) : "v"(lo), "v"(hi));
  return r;
}
// byte-permute: D bytes from {S0=a, S1=b}; sel values 0-3 = b bytes, 4-7 = a bytes
__device__ __forceinline__ uint32_t perm2(uint32_t a, uint32_t b, uint32_t sel) {
  uint32_t r;
  asm("v_perm_b32 %0, %1, %2, %3" : "=v"(r) : "v"(a), "v"(b), "s"(sel));
  return r;
}

// load 8 consecutive "bf16-worth" elements starting at p (packed 2/dword)
__device__ __forceinline__ void load8bf(const uint16_t* p, uint32_t o[4]) {
  i32x4 v = *reinterpret_cast<const i32x4*>(p);
  o[0] = (uint32_t)v[0]; o[1] = (uint32_t)v[1]; o[2] = (uint32_t)v[2]; o[3] = (uint32_t)v[3];
}
__device__ __forceinline__ void load8bf(const float* p, uint32_t o[4]) {
  float4 a = *reinterpret_cast<const float4*>(p);
  float4 b = *reinterpret_cast<const float4*>(p + 4);
  o[0] = cvtpk(a.x, a.y);
  o[1] = cvtpk(a.z, a.w);
  o[2] = cvtpk(b.x, b.y);
  o[3] = cvtpk(b.z, b.w);
}

// fused K+V fp32 -> bf16 conversion (one launch)
__global__ void cvt2_kernel(const float* __restrict__ inK, const float* __restrict__ inV,
                            uint16_t* __restrict__ outK, uint16_t* __restrict__ outV, int n4) {
  int i = blockIdx.x * blockDim.x + threadIdx.x;
  int stride = gridDim.x * blockDim.x;
  for (int j = i; j < 2 * n4; j += stride) {
    const float* in = (j < n4) ? inK : inV;
    uint16_t* out   = (j < n4) ? outK : outV;
    int jj = (j < n4) ? j : j - n4;
    float4 v = reinterpret_cast<const float4*>(in)[jj];
    uint2 o;
    o.x = cvtpk(v.x, v.y);
    o.y = cvtpk(v.z, v.w);
    reinterpret_cast<uint2*>(out)[jj] = o;
  }
}

// V^T LDS column swizzle: conflict-free (<=2-way) for both the transpose-scatter
// writes (spread by d>>3) and the PV b-frag reads (spread by d&7)
#define VSWZ(d) (((((uint32_t)(d) >> 3) ^ (uint32_t)(d)) & 7u) << 3)

template <typename KVT>
__launch_bounds__(256, 2)
__global__ void attn_kernel(const float* __restrict__ Q,
                            const KVT* __restrict__ Ksrc,
                            const KVT* __restrict__ Vsrc,
                            const float* __restrict__ sinks,
                            float* __restrict__ out) {
  // LDS: K tiles  2 x (32 x 256B, 16B-swizzled)   : 16 KB   @ 0
  //      V^T tiles 2 x (128 x 64B, 8B-swizzled)   : 16 KB   @ 16384
  //      P scratch, 2 KB per wave (8B-swizzled)   : 8 KB    @ 32768
  __shared__ __align__(16) uint8_t smem[40960];

  const int tid  = threadIdx.x;
  const int lane = tid & 63;
  const int wv   = tid >> 6;
  const int c    = lane & 15;   // "16-dim" lane coordinate
  const int g    = lane >> 4;   // lane group 0..3
  uint8_t* pls = smem + 32768 + wv * 2048;

  // ---- block decode: kv = bid&7 keeps each kv's K/V on one XCD's L2 ----
  const int bid = blockIdx.x;
  const int kv  = bid & 7;
  const int i2  = bid >> 3;          // 0 .. 48*B-1
  const int b   = i2 / 48;
  const int pairIdx = i2 % 48;
  const int head = kv * NQM + wv;
  const float sink_l2 = sinks[head] * 1.4426950408889634f;

  // tile pairing: work(qt) = qt+1 tiles for qt<32, 33 for qt>=32.
  // pair (31-p, p) -> 33; singles 32..63 -> 33. Every block = 33 k-iters.
  int qtA, qtB, nrep;
  if (pairIdx < 16) { qtA = 31 - pairIdx; qtB = pairIdx; nrep = 2; }
  else              { qtA = pairIdx + 16; qtB = 0;       nrep = 1; }

  // ---------------- staging coordinates ----------------
  const int kr  = tid >> 3;            // K row 0..31 (fp32 path)
  const int kcB = (tid & 7) * 32;      // K column byte (fp32 path)
  const uint32_t kw0 = (uint32_t)(kr * 256 + ((kcB)      ^ ((kr & 7) << 4)));
  const uint32_t kw1 = (uint32_t)(kr * 256 + ((kcB + 16) ^ ((kr & 7) << 4)));
  const KVT* kg = Ksrc + (size_t)(b * S_LEN) * KVROW + kv * HD + (tid & 7) * 16;
  const size_t kbase = (size_t)(b * S_LEN) * KVROW + kv * HD;   // elems
  const int va = tid >> 4;             // V key-pair 0..15
  const int vd = tid & 15;             // V d-chunk
  const KVT* vg = Vsrc + (size_t)(b * S_LEN) * KVROW + kv * HD + vd * 8;

  uint32_t vr0[4], vr1[4];

  // async K stage: linear LDS dest (wave-uniform base + lane*16), swizzle
  // applied on the per-lane GLOBAL source address (m173 pattern)
  auto stageK = [&](uint8_t* kbuf, int kt) {
    if constexpr (sizeof(KVT) == 2) {
      #pragma unroll
      for (int ch = 0; ch < 2; ++ch) {
        const int o    = wv * 2048 + ch * 1024 + lane * 16;
        const int row  = o >> 8;
        const int scol = (o & 255) ^ ((row & 7) << 4);
        const uint8_t* gp = (const uint8_t*)(Ksrc + kbase + (size_t)(kt + row) * KVROW) + scol;
        __builtin_amdgcn_global_load_lds(
            (const __attribute__((address_space(1))) void*)gp,
            (__attribute__((address_space(3))) void*)(kbuf + wv * 2048 + ch * 1024),
            16, 0, 0);
      }
    } else {
      const KVT* src = kg + (size_t)(kt + kr) * KVROW;
      uint32_t t0[4], t1[4];
      load8bf(src, t0); load8bf(src + 8, t1);
      i32x4 w0, w1;
      w0[0]=(int)t0[0]; w0[1]=(int)t0[1]; w0[2]=(int)t0[2]; w0[3]=(int)t0[3];
      w1[0]=(int)t1[0]; w1[1]=(int)t1[1]; w1[2]=(int)t1[2]; w1[3]=(int)t1[3];
      *reinterpret_cast<i32x4*>(kbuf + kw0) = w0;
      *reinterpret_cast<i32x4*>(kbuf + kw1) = w1;
    }
  };
  auto loadV = [&](int kt) {
    const KVT* vs = vg + (size_t)(kt + 2 * va) * KVROW;
    load8bf(vs, vr0); load8bf(vs + KVROW, vr1);
  };
  // transpose-repack via v_perm_b32: out dword d = {r1.half, r0.half}
  auto writeV = [&](uint8_t* vbuf) {
    #pragma unroll
    for (int ii = 0; ii < 8; ++ii) {
      int d = vd * 8 + ii;
      uint32_t w = (ii & 1) ? perm2(vr1[ii >> 1], vr0[ii >> 1], 0x07060302u)
                            : perm2(vr1[ii >> 1], vr0[ii >> 1], 0x05040100u);
      uint32_t byte = (uint32_t)(d * 64) + (((uint32_t)(va * 4)) ^ VSWZ(d));
      *reinterpret_cast<uint32_t*>(vbuf + byte) = w;
    }
  };

  const float SCALE2 = 0.08838834764831845f * 1.4426950408889634f;  // 1/sqrt(128)*log2e
  const uint32_t sp = ((uint32_t)(c & 7)) << 3;   // P swizzle (row&7 == c&7)

  for (int rep = 0; rep < nrep; ++rep) {
    const int q0 = (rep ? qtB : qtA) * QB;

    // -------- Q fragments (bf16, SM_SCALE*log2e folded in) --------
    bf16x8 qf[2][4];
    #pragma unroll
    for (int tq = 0; tq < 2; ++tq) {
      const float* qp = Q + (size_t)(b * S_LEN + q0 + tq * 16 + c) * QROW + head * HD;
      #pragma unroll
      for (int f = 0; f < 4; ++f) {
        int d0 = f * 32 + g * 8;
        float4 a = *reinterpret_cast<const float4*>(qp + d0);
        float4 bb = *reinterpret_cast<const float4*>(qp + d0 + 4);
        i32x4 t;
        t[0] = (int)cvtpk(a.x * SCALE2, a.y * SCALE2);
        t[1] = (int)cvtpk(a.z * SCALE2, a.w * SCALE2);
        t[2] = (int)cvtpk(bb.x * SCALE2, bb.y * SCALE2);
        t[3] = (int)cvtpk(bb.z * SCALE2, bb.w * SCALE2);
        qf[tq][f] = __builtin_bit_cast(bf16x8, t);
      }
    }

    // online-softmax state (log2 domain); sink = initial column with weight 1,
    // split 0.25 per g-lane (lp is a per-lane partial of l, reduced at epilogue)
    float m_[2] = {sink_l2, sink_l2};
    float lp_[2] = {0.25f, 0.25f};
    f32x4 acc[2][8];
    #pragma unroll
    for (int tq = 0; tq < 2; ++tq)
      #pragma unroll
      for (int dt = 0; dt < 8; ++dt) acc[tq][dt] = (f32x4)0.0f;

    int kstart = q0 - (WIN - 1);
    if (kstart < 0) kstart = 0;
    kstart &= ~(KTILE - 1);

    uint8_t* kcur = smem;         uint8_t* kalt = smem + 8192;
    uint8_t* vcur = smem + 16384; uint8_t* valt = smem + 24576;

    // prologue: stage first tile
    loadV(kstart);
    stageK(kcur, kstart);
    writeV(vcur);
    __syncthreads();

    for (int kt = kstart; kt <= q0; kt += KTILE) {
      const bool more = (kt + KTILE) <= q0;
      if (more) {           // issue next tile's loads EARLY (K async, V to regs)
        stageK(kalt, kt + KTILE);
        loadV(kt + KTILE);
      }

      // ---- QK^T (swapped: St[key][q]) ----
      f32x4 st[2][2];
      #pragma unroll
      for (int a_ = 0; a_ < 2; ++a_)
        #pragma unroll
        for (int b_ = 0; b_ < 2; ++b_) st[a_][b_] = (f32x4)0.0f;

      __builtin_amdgcn_s_setprio(1);
      #pragma unroll
      for (int kt_ = 0; kt_ < 2; ++kt_) {
        bf16x8 kf[4];
        #pragma unroll
        for (int f = 0; f < 4; ++f) {
          int row = kt_ * 16 + c;
          uint32_t byte = (uint32_t)(row * 256 + ((f * 64 + g * 16) ^ ((row & 7) << 4)));
          kf[f] = *reinterpret_cast<const bf16x8*>(kcur + byte);
        }
        #pragma unroll
        for (int tq = 0; tq < 2; ++tq)
          #pragma unroll
          for (int f = 0; f < 4; ++f)
            st[kt_][tq] = __builtin_amdgcn_mfma_f32_16x16x32_bf16(kf[f], qf[tq][f], st[kt_][tq], 0, 0, 0);
      }
      __builtin_amdgcn_s_setprio(0);

      // ---- mask (edge tiles only; wave-uniform branch) ----
      const bool need_mask = (kt + KTILE - 1 > q0) || (kt < q0 + QB - WIN);
      if (need_mask) {
        #pragma unroll
        for (int kt_ = 0; kt_ < 2; ++kt_)
          #pragma unroll
          for (int tq = 0; tq < 2; ++tq)
            #pragma unroll
            for (int r = 0; r < 4; ++r) {
              int k_ = kt + kt_ * 16 + g * 4 + r;
              int q_ = q0 + tq * 16 + c;
              bool ok = (k_ <= q_) && (k_ > q_ - WIN);
              if (!ok) st[kt_][tq][r] = -1e38f;
            }
      }

      // ---- online softmax (log2 domain, defer-rescale, lazy cross-lane) ----
      #pragma unroll
      for (int tq = 0; tq < 2; ++tq) {
        float ownmax = fmaxf(fmaxf(fmaxf(st[0][tq][0], st[0][tq][1]), fmaxf(st[0][tq][2], st[0][tq][3])),
                             fmaxf(fmaxf(st[1][tq][0], st[1][tq][1]), fmaxf(st[1][tq][2], st[1][tq][3])));
        const float mold = m_[tq];
        // wave-wide check needs no row reduction: all-lanes-below == all-rows-below
        if (!__all(ownmax <= mold + 11.54f)) {   // T13: P bounded by 2^11.54 = e^8
          float vmax = fmaxf(ownmax, __shfl_xor(ownmax, 16));
          vmax = fmaxf(vmax, __shfl_xor(vmax, 32));
          float mnew = fmaxf(mold, vmax);
          float scl  = exp2f(mold - mnew);
          m_[tq] = mnew;
          lp_[tq] *= scl;
          float sc[4];
          #pragma unroll
          for (int r = 0; r < 4; ++r) sc[r] = __shfl(scl, (lane & 48) | (g * 4 + r));
          #pragma unroll
          for (int dt = 0; dt < 8; ++dt)
            #pragma unroll
            for (int r = 0; r < 4; ++r) acc[tq][dt][r] *= sc[r];
        }
        const float mrun = m_[tq];
        float p[2][4];
        float s = 0.0f;
        #pragma unroll
        for (int kt_ = 0; kt_ < 2; ++kt_)
          #pragma unroll
          for (int r = 0; r < 4; ++r) {
            float e = exp2f(st[kt_][tq][r] - mrun);
            p[kt_][r] = e;
            s += e;
          }
        lp_[tq] += s;                       // per-lane partial; reduced at epilogue
        #pragma unroll
        for (int kt_ = 0; kt_ < 2; ++kt_) {
          uint2 pk;
          pk.x = cvtpk(p[kt_][0], p[kt_][1]);
          pk.y = cvtpk(p[kt_][2], p[kt_][3]);
          uint32_t byte = (uint32_t)((tq * 16 + c) * 64) + (((uint32_t)(kt_ * 32 + g * 8)) ^ sp);
          *reinterpret_cast<uint2*>(pls + byte) = pk;
        }
      }

      // ---- PV ----
      bf16x8 pa[2];
      #pragma unroll
      for (int tq = 0; tq < 2; ++tq) {
        uint32_t base = (uint32_t)((tq * 16 + c) * 64);
        uint2 plo = *reinterpret_cast<const uint2*>(pls + base + (((uint32_t)(g * 16))     ^ sp));
        uint2 phi = *reinterpret_cast<const uint2*>(pls + base + (((uint32_t)(g * 16 + 8)) ^ sp));
        i32x4 pv; pv[0] = (int)plo.x; pv[1] = (int)plo.y; pv[2] = (int)phi.x; pv[3] = (int)phi.y;
        pa[tq] = __builtin_bit_cast(bf16x8, pv);
      }
      __builtin_amdgcn_s_setprio(1);
      #pragma unroll
      for (int dt = 0; dt < 8; ++dt) {
        int d = dt * 16 + c;
        uint32_t rowb = (uint32_t)(d * 64);
        uint32_t swz  = VSWZ(d);
        uint2 lo = *reinterpret_cast<const uint2*>(vcur + rowb + (((uint32_t)(g * 16))     ^ swz));
        uint2 hi = *reinterpret_cast<const uint2*>(vcur + rowb + (((uint32_t)(g * 16 + 8)) ^ swz));
        i32x4 vv; vv[0] = (int)lo.x; vv[1] = (int)lo.y; vv[2] = (int)hi.x; vv[3] = (int)hi.y;
        bf16x8 vf = __builtin_bit_cast(bf16x8, vv);
        #pragma unroll
        for (int tq = 0; tq < 2; ++tq)
          acc[tq][dt] = __builtin_amdgcn_mfma_f32_16x16x32_bf16(pa[tq], vf, acc[tq][dt], 0, 0, 0);
      }
      __builtin_amdgcn_s_setprio(0);

      // ---- write next V tile into alternate buffer (T14 write-late) ----
      if (more) writeV(valt);
      __syncthreads();
      uint8_t* t0 = kcur; kcur = kalt; kalt = t0;
      uint8_t* t1 = vcur; vcur = valt; valt = t1;
    }

    // -------- epilogue: reduce l across g-lanes, O /= l, store --------
    #pragma unroll
    for (int tq = 0; tq < 2; ++tq) {
      float lt = lp_[tq];
      lt += __shfl_xor(lt, 16);
      lt += __shfl_xor(lt, 32);
      float linv = 1.0f / lt;
      float li[4];
      #pragma unroll
      for (int r = 0; r < 4; ++r) li[r] = __shfl(linv, (lane & 48) | (g * 4 + r));
      #pragma unroll
      for (int dt = 0; dt < 8; ++dt)
        #pragma unroll
        for (int r = 0; r < 4; ++r) {
          size_t o = (size_t)(b * S_LEN + q0 + tq * 16 + g * 4 + r) * QROW + head * HD + dt * 16 + c;
          out[o] = acc[tq][dt][r] * li[r];
        }
    }
  }
}

extern "C" void kernel_launch(void* const* d_in, const int* in_sizes, int n_in,
                              void* d_out, int out_size, void* d_ws, size_t ws_size,
                              hipStream_t stream) {
  const float* Q     = (const float*)d_in[0];
  const float* K     = (const float*)d_in[1];
  const float* V     = (const float*)d_in[2];
  const float* sinks = (const float*)d_in[3];
  float* out = (float*)d_out;

  const int nK = in_sizes[1];                       // B*S*NKV*HD
  const int B  = in_sizes[0] / (S_LEN * QROW);
  dim3 grid(384 * B);                               // 48 uniform blocks per (kv,b)

  const size_t need = (size_t)nK * 2u * 2u;         // Kbf + Vbf in bf16
  if (ws_size >= need) {
    uint16_t* Kb = (uint16_t*)d_ws;
    uint16_t* Vb = Kb + nK;
    cvt2_kernel<<<1024, 256, 0, stream>>>(K, V, Kb, Vb, nK / 4);
    attn_kernel<uint16_t><<<grid, 256, 0, stream>>>(Q, Kb, Vb, sinks, out);
  } else {
    attn_kernel<float><<<grid, 256, 0, stream>>>(Q, K, V, sinks, out);
  }
}